// Round 1
// baseline (323.991 us; speedup 1.0000x reference)
//
#include <hip/hip_runtime.h>

typedef unsigned short u16;
typedef float f32x4 __attribute__((ext_vector_type(4)));
typedef __bf16 bf16x8 __attribute__((ext_vector_type(8)));

#define EPS_ 1e-6f

__device__ __forceinline__ u16 f2bf(float f) {
    unsigned u = __float_as_uint(f);
    u += 0x7FFFu + ((u >> 16) & 1u);   // round-to-nearest-even
    return (u16)(u >> 16);
}
__device__ __forceinline__ float bf2f(u16 h) {
    return __uint_as_float(((unsigned)h) << 16);
}
__device__ __forceinline__ void gload_lds16(const void* g, void* l) {
    __builtin_amdgcn_global_load_lds(
        (const __attribute__((address_space(1))) void*)g,
        (__attribute__((address_space(3))) void*)l, 16, 0, 0);
}

// ---------------- fp32 -> bf16 convert (vectorized) ----------------
__global__ __launch_bounds__(256) void f32_to_bf16_kernel(
    const float* __restrict__ src, u16* __restrict__ dst, int n4)
{
    int i = blockIdx.x * 256 + threadIdx.x;
    if (i >= n4) return;
    float4 f = ((const float4*)src)[i];
    ushort4 o;
    o.x = f2bf(f.x); o.y = f2bf(f.y); o.z = f2bf(f.z); o.w = f2bf(f.w);
    ((ushort4*)dst)[i] = o;
}

// ---------------- GEMM: C[M,N] = A[M,K] @ B[N,K]^T + bias, optional phi ----------
// A,B bf16 row-major (both K-contiguous). 128x128 tile, BK=64, 4 waves (2x2 of 64x64).
// global_load_lds width 16 with XOR-swizzled SOURCE (linear LDS dest) + same-XOR read:
// conflict-free ds_read_b128 fragments.
__global__ __launch_bounds__(256) void gemm_bt(
    const u16* __restrict__ A, const u16* __restrict__ B,
    const float* __restrict__ bias, u16* __restrict__ outbf,
    float* __restrict__ outf, int M, int N, int K, int dophi)
{
    __shared__ __align__(16) u16 As[128 * 64];
    __shared__ __align__(16) u16 Bs[128 * 64];
    const int tid  = threadIdx.x;
    const int lane = tid & 63;
    const int wv   = tid >> 6;
    const int wm   = wv >> 1, wn = wv & 1;

    const u16* Ab = A + (size_t)blockIdx.y * 128 * K;
    const u16* Bb = B + (size_t)blockIdx.x * 128 * K;

    f32x4 acc[4][4];
    #pragma unroll
    for (int m = 0; m < 4; ++m)
        #pragma unroll
        for (int n = 0; n < 4; ++n) {
            acc[m][n][0] = 0.f; acc[m][n][1] = 0.f;
            acc[m][n][2] = 0.f; acc[m][n][3] = 0.f;
        }

    for (int kt = 0; kt < K; kt += 64) {
        #pragma unroll
        for (int i = 0; i < 4; ++i) {
            int ch   = wv * 4 + i;               // 16 chunks of 1KB per 16KB tile
            int row  = ch * 8 + (lane >> 3);     // 8 rows per chunk
            int slot = lane & 7;                 // 16B slot within 128B row
            int ksrc = kt + ((slot ^ (row & 7)) << 3);  // pre-swizzled source
            gload_lds16(Ab + (size_t)row * K + ksrc, (char*)As + ch * 1024);
            gload_lds16(Bb + (size_t)row * K + ksrc, (char*)Bs + ch * 1024);
        }
        __syncthreads();
        #pragma unroll
        for (int kk = 0; kk < 2; ++kk) {
            const int kslot = (lane >> 4) + kk * 4;
            bf16x8 af[4], bfm[4];
            #pragma unroll
            for (int m = 0; m < 4; ++m) {
                int row = wm * 64 + m * 16 + (lane & 15);
                af[m] = *(const bf16x8*)((const char*)As + row * 128 +
                                         ((kslot ^ (row & 7)) << 4));
            }
            #pragma unroll
            for (int n = 0; n < 4; ++n) {
                int col = wn * 64 + n * 16 + (lane & 15);
                bfm[n] = *(const bf16x8*)((const char*)Bs + col * 128 +
                                          ((kslot ^ (col & 7)) << 4));
            }
            #pragma unroll
            for (int m = 0; m < 4; ++m)
                #pragma unroll
                for (int n = 0; n < 4; ++n)
                    acc[m][n] = __builtin_amdgcn_mfma_f32_16x16x32_bf16(
                        af[m], bfm[n], acc[m][n], 0, 0, 0);
        }
        __syncthreads();
    }

    // epilogue: C/D frag: col = lane&15, row = (lane>>4)*4 + j  [m89-verified]
    #pragma unroll
    for (int n = 0; n < 4; ++n) {
        int col = blockIdx.x * 128 + wn * 64 + n * 16 + (lane & 15);
        float bb = bias[col];
        #pragma unroll
        for (int m = 0; m < 4; ++m) {
            int row0 = blockIdx.y * 128 + wm * 64 + m * 16 + ((lane >> 4) << 2);
            #pragma unroll
            for (int j = 0; j < 4; ++j) {
                float v = acc[m][n][j] + bb;
                if (dophi) v = (v > 0.f) ? (v + 1.f) : __expf(v);  // elu(x)+1
                size_t off = (size_t)(row0 + j) * N + col;
                if (outf) outf[off] = v; else outbf[off] = f2bf(v);
            }
        }
    }
}

// ---------------- kv partial: kv[b,h,d,m] = sum_s k*v ; ksum[b,h,d] = sum_s k -----
// grid (64 bh, 16 s-chunks), 256 thr as 16x16 grid of 4x4 register cells, fp32 accum.
__global__ __launch_bounds__(256) void kv_partial(
    const u16* __restrict__ kbf, const u16* __restrict__ vbf,
    const float* __restrict__ mask, float* __restrict__ kvp, float* __restrict__ ksp)
{
    const int bh = blockIdx.x, ch = blockIdx.y;
    const int b = bh >> 4, h = bh & 15;
    const int tid = threadIdx.x;
    __shared__ __align__(16) float ks[8][64];
    __shared__ __align__(16) float vs[8][64];
    const int dg = tid >> 4, mg = tid & 15;
    float acc[4][4] = {};
    float ksa[4] = {};
    const int s0 = ch * 256;
    const int jj = tid >> 6, e = tid & 63;
    for (int sb = 0; sb < 256; sb += 8) {
        #pragma unroll
        for (int r = jj; r < 8; r += 4) {
            size_t grow = (size_t)b * 4096 + (s0 + sb + r);
            float mm = mask[grow];
            size_t off = (grow << 10) + (h << 6) + e;
            ks[r][e] = bf2f(kbf[off]) * mm;
            vs[r][e] = bf2f(vbf[off]) * mm;
        }
        __syncthreads();
        #pragma unroll
        for (int ss = 0; ss < 8; ++ss) {
            float4 k4 = *(const float4*)&ks[ss][dg << 2];
            float4 v4 = *(const float4*)&vs[ss][mg << 2];
            float ka[4] = {k4.x, k4.y, k4.z, k4.w};
            float va[4] = {v4.x, v4.y, v4.z, v4.w};
            #pragma unroll
            for (int di = 0; di < 4; ++di) {
                ksa[di] += ka[di];
                #pragma unroll
                for (int mi = 0; mi < 4; ++mi) acc[di][mi] += ka[di] * va[mi];
            }
        }
        __syncthreads();
    }
    float* o = kvp + (((size_t)ch * 64 + bh) << 12);
    #pragma unroll
    for (int di = 0; di < 4; ++di)
        #pragma unroll
        for (int mi = 0; mi < 4; ++mi)
            o[(dg * 4 + di) * 64 + (mg * 4 + mi)] = acc[di][mi];
    if (mg == 0) {
        float* os = ksp + (((size_t)ch * 64 + bh) << 6);
        #pragma unroll
        for (int di = 0; di < 4; ++di) os[dg * 4 + di] = ksa[di];
    }
}

// ---------------- reduce 16 partials -> kv^T (bf16) + ksum (bf16) ----------------
__global__ __launch_bounds__(256) void kv_reduce(
    const float* __restrict__ kvp, const float* __restrict__ ksp,
    u16* __restrict__ kvTbf, u16* __restrict__ ksumbf)
{
    const int bh = blockIdx.x, tid = threadIdx.x;
    for (int idx = tid; idx < 4096; idx += 256) {
        float s = 0.f;
        #pragma unroll
        for (int c = 0; c < 16; ++c) s += kvp[(((size_t)c * 64 + bh) << 12) + idx];
        int d = idx >> 6, m = idx & 63;
        kvTbf[((size_t)bh << 12) + (m << 6) + d] = f2bf(s);   // transposed: [m][d]
    }
    if (tid < 64) {
        float s = 0.f;
        #pragma unroll
        for (int c = 0; c < 16; ++c) s += ksp[(((size_t)c * 64 + bh) << 6) + tid];
        ksumbf[(bh << 6) + tid] = f2bf(s);
    }
}

// ---------------- attn: out[s,m] = (sum_d q[s,d] kv[d,m]) / (q . ksum + eps) ------
// MFMA: A = q rows (direct from global), B = kv^T (LDS, swizzled), plus one extra
// B-fragment with ksum in col 0 -> normalizer lands in C col 0, shfl-broadcast.
__global__ __launch_bounds__(256) void attn_kernel(
    const u16* __restrict__ qbf, const u16* __restrict__ kvTbf,
    const u16* __restrict__ ksumbf, u16* __restrict__ attnbf)
{
    const int bh = blockIdx.x;
    const int b = bh >> 4, h = bh & 15;
    const int tid = threadIdx.x, lane = tid & 63, wv = tid >> 6;
    __shared__ __align__(16) u16 kvs[64 * 64];
    __shared__ __align__(16) u16 kss[64];

    {
        const uint4* src = (const uint4*)(kvTbf + ((size_t)bh << 12));
        for (int u = tid; u < 512; u += 256) {
            uint4 d4 = src[u];
            int m = u >> 3, slot = u & 7;
            *(uint4*)((char*)kvs + m * 128 + ((slot ^ (m & 7)) << 4)) = d4;
        }
        if (tid < 32)
            ((unsigned*)kss)[tid] = ((const unsigned*)(ksumbf + ((size_t)bh << 6)))[tid];
    }
    __syncthreads();

    bf16x8 bfr[2][4], bnf[2];
    #pragma unroll
    for (int kk = 0; kk < 2; ++kk) {
        int kslot = kk * 4 + (lane >> 4);
        #pragma unroll
        for (int n = 0; n < 4; ++n) {
            int m = n * 16 + (lane & 15);
            bfr[kk][n] = *(const bf16x8*)((const char*)kvs + m * 128 +
                                          ((kslot ^ (m & 7)) << 4));
        }
        #pragma unroll
        for (int i2 = 0; i2 < 8; ++i2) bnf[kk][i2] = (__bf16)0.0f;
        if ((lane & 15) == 0)
            bnf[kk] = *(const bf16x8*)((const char*)kss + (kslot << 4));
    }

    const int sbase = blockIdx.y * 256 + wv * 16;
    for (int it = 0; it < 4; ++it) {
        const int st = sbase + it * 64;
        f32x4 acc[4], nacc;
        #pragma unroll
        for (int n = 0; n < 4; ++n) {
            acc[n][0] = 0.f; acc[n][1] = 0.f; acc[n][2] = 0.f; acc[n][3] = 0.f;
        }
        nacc[0] = 0.f; nacc[1] = 0.f; nacc[2] = 0.f; nacc[3] = 0.f;
        #pragma unroll
        for (int kk = 0; kk < 2; ++kk) {
            size_t goff = (((size_t)(b * 4096 + st + (lane & 15))) << 10) +
                          (h << 6) + kk * 32 + ((lane >> 4) << 3);
            bf16x8 af = *(const bf16x8*)(qbf + goff);
            #pragma unroll
            for (int n = 0; n < 4; ++n)
                acc[n] = __builtin_amdgcn_mfma_f32_16x16x32_bf16(af, bfr[kk][n], acc[n], 0, 0, 0);
            nacc = __builtin_amdgcn_mfma_f32_16x16x32_bf16(af, bnf[kk], nacc, 0, 0, 0);
        }
        float inv[4];
        #pragma unroll
        for (int j = 0; j < 4; ++j) {
            float nj = __shfl(nacc[j], lane & 48);   // col-0 holder of this 16-lane group
            inv[j] = 1.0f / (nj + EPS_);
        }
        #pragma unroll
        for (int n = 0; n < 4; ++n)
            #pragma unroll
            for (int j = 0; j < 4; ++j) {
                int row = st + ((lane >> 4) << 2) + j;
                attnbf[(((size_t)(b * 4096 + row)) << 10) + (h << 6) + n * 16 + (lane & 15)]
                    = f2bf(acc[n][j] * inv[j]);
            }
    }
}

extern "C" void kernel_launch(void* const* d_in, const int* in_sizes, int n_in,
                              void* d_out, int out_size, void* d_ws, size_t ws_size,
                              hipStream_t stream) {
    const float* x    = (const float*)d_in[0];
    const float* mask = (const float*)d_in[1];
    const float* Wq   = (const float*)d_in[2];
    const float* bq   = (const float*)d_in[3];
    const float* Wk   = (const float*)d_in[4];
    const float* bk   = (const float*)d_in[5];
    const float* Wv   = (const float*)d_in[6];
    const float* bv   = (const float*)d_in[7];
    const float* Wo   = (const float*)d_in[8];
    const float* bo   = (const float*)d_in[9];
    float* out = (float*)d_out;

    if (ws_size < 142606336u) return;  // need 136 MiB

    char* ws = (char*)d_ws;
    // region 0 [0, 32MB): xbf during projections; then reused for kv partials/finals
    u16*   xbf    = (u16*)ws;
    float* kvp    = (float*)ws;                   // 16 MB (after xbf dead)
    float* ksp    = (float*)(ws + 16777216);      // 256 KB
    u16*   kvTbf  = (u16*)(ws + 17039360);        // 512 KB
    u16*   ksumbf = (u16*)(ws + 17563648);        // 8 KB
    u16*   wqbf   = (u16*)(ws + 33554432);        // 2 MB each
    u16*   wkbf   = (u16*)(ws + 35651584);
    u16*   wvbf   = (u16*)(ws + 37748736);
    u16*   wobf   = (u16*)(ws + 39845888);
    u16*   qbf    = (u16*)(ws + 41943040);        // 32 MB
    u16*   kbf    = qbf + 16777216;               // 32 MB
    u16*   vbf    = kbf + 16777216;               // 32 MB
    u16*   attnbf = kbf;                          // reuse (k dead after kv_partial)

    // converts
    f32_to_bf16_kernel<<<16384, 256, 0, stream>>>(x,  xbf,  16777216 / 4);
    f32_to_bf16_kernel<<<1024,  256, 0, stream>>>(Wq, wqbf, 1048576 / 4);
    f32_to_bf16_kernel<<<1024,  256, 0, stream>>>(Wk, wkbf, 1048576 / 4);
    f32_to_bf16_kernel<<<1024,  256, 0, stream>>>(Wv, wvbf, 1048576 / 4);
    f32_to_bf16_kernel<<<1024,  256, 0, stream>>>(Wo, wobf, 1048576 / 4);

    // projections (phi on q,k)
    dim3 gg(8, 128);
    gemm_bt<<<gg, 256, 0, stream>>>(xbf, wqbf, bq, qbf, nullptr, 16384, 1024, 1024, 1);
    gemm_bt<<<gg, 256, 0, stream>>>(xbf, wkbf, bk, kbf, nullptr, 16384, 1024, 1024, 1);
    gemm_bt<<<gg, 256, 0, stream>>>(xbf, wvbf, bv, vbf, nullptr, 16384, 1024, 1024, 0);

    // kv / ksum
    kv_partial<<<dim3(64, 16), 256, 0, stream>>>(kbf, vbf, mask, kvp, ksp);
    kv_reduce<<<64, 256, 0, stream>>>(kvp, ksp, kvTbf, ksumbf);

    // qkv + normalizer
    attn_kernel<<<dim3(64, 16), 256, 0, stream>>>(qbf, kvTbf, ksumbf, attnbf);

    // output projection -> fp32 d_out
    gemm_bt<<<gg, 256, 0, stream>>>(attnbf, wobf, bo, nullptr, out, 16384, 1024, 1024, 0);
}

// Round 2
// 278.829 us; speedup vs baseline: 1.1620x; 1.1620x over previous
//
#include <hip/hip_runtime.h>

typedef unsigned short u16;
typedef float f32x4 __attribute__((ext_vector_type(4)));
typedef __bf16 bf16x8 __attribute__((ext_vector_type(8)));

#define EPS_ 1e-6f

__device__ __forceinline__ u16 f2bf(float f) {
    unsigned u = __float_as_uint(f);
    u += 0x7FFFu + ((u >> 16) & 1u);   // round-to-nearest-even
    return (u16)(u >> 16);
}
__device__ __forceinline__ float bf2f(u16 h) {
    return __uint_as_float(((unsigned)h) << 16);
}
__device__ __forceinline__ void gload_lds16(const void* g, void* l) {
    __builtin_amdgcn_global_load_lds(
        (const __attribute__((address_space(1))) void*)g,
        (__attribute__((address_space(3))) void*)l, 16, 0, 0);
}

// ---------------- fp32 -> bf16 convert (vectorized) ----------------
__global__ __launch_bounds__(256) void f32_to_bf16_kernel(
    const float* __restrict__ src, u16* __restrict__ dst, int n4)
{
    int i = blockIdx.x * 256 + threadIdx.x;
    if (i >= n4) return;
    float4 f = ((const float4*)src)[i];
    ushort4 o;
    o.x = f2bf(f.x); o.y = f2bf(f.y); o.z = f2bf(f.z); o.w = f2bf(f.w);
    ((ushort4*)dst)[i] = o;
}

// =================================================================
// 256x256 8-phase GEMM: C[M,N] = A[M,K] @ B[N,K]^T + bias
// MODE 1: split-write bf16 to q/k/v (phi on col<2048).  MODE 0: fp32 to outf.
// 8 waves (2M x 4N), BK=64 in two 32-k halves, double-buffered 128 KiB LDS,
// counted vmcnt(8), setprio around MFMA, XOR-swizzled staging (both sides).
// Swapped MFMA operands: lane holds 4 consecutive output COLUMNS.
// =================================================================

// stage one 16KB half-tile (256 rows x 32 k-elems) : 2 x global_load_lds(16B)/thread
__device__ __forceinline__ void stage_half(
    const u16* __restrict__ src, int K, int kbase, char* slot, int tid)
{
    const int w = tid >> 6, l = tid & 63;
    #pragma unroll
    for (int j = 0; j < 2; ++j) {
        int row = j * 128 + w * 16 + (l >> 2);
        int c   = l & 3;
        int sw  = (row & 3) ^ ((row >> 2) & 3);
        const u16* g = src + (size_t)row * K + kbase + ((c ^ sw) << 3);
        gload_lds16(g, slot + j * 8192 + w * 1024);
    }
}

#define BARRIER()  asm volatile("s_barrier" ::: "memory")
#define VMCNT8()   asm volatile("s_waitcnt vmcnt(8)" ::: "memory")
#define LGKM0()    asm volatile("s_waitcnt lgkmcnt(0)" ::: "memory")

#define LOADA(base, MOFF) \
    af0 = *(const bf16x8*)((base) + aoff + (MOFF) + 0);    \
    af1 = *(const bf16x8*)((base) + aoff + (MOFF) + 1024); \
    af2 = *(const bf16x8*)((base) + aoff + (MOFF) + 2048); \
    af3 = *(const bf16x8*)((base) + aoff + (MOFF) + 3072);

#define LOADB(base) \
    bf0 = *(const bf16x8*)((base) + boff + 0);    \
    bf1 = *(const bf16x8*)((base) + boff + 1024); \
    bf2 = *(const bf16x8*)((base) + boff + 2048); \
    bf3 = *(const bf16x8*)((base) + boff + 3072);

#define MFMA1(M_, N_, AF_, BF_) \
    acc[M_][N_] = __builtin_amdgcn_mfma_f32_16x16x32_bf16(BF_, AF_, acc[M_][N_], 0, 0, 0)

#define MFMA_BLOCK(M0) do { \
    MFMA1(M0+0, 0, af0, bf0); MFMA1(M0+0, 1, af0, bf1); MFMA1(M0+0, 2, af0, bf2); MFMA1(M0+0, 3, af0, bf3); \
    MFMA1(M0+1, 0, af1, bf0); MFMA1(M0+1, 1, af1, bf1); MFMA1(M0+1, 2, af1, bf2); MFMA1(M0+1, 3, af1, bf3); \
    MFMA1(M0+2, 0, af2, bf0); MFMA1(M0+2, 1, af2, bf1); MFMA1(M0+2, 2, af2, bf2); MFMA1(M0+2, 3, af2, bf3); \
    MFMA1(M0+3, 0, af3, bf0); MFMA1(M0+3, 1, af3, bf1); MFMA1(M0+3, 2, af3, bf2); MFMA1(M0+3, 3, af3, bf3); \
} while (0)

template<int MODE>
__global__ __launch_bounds__(512, 2) void gemm8p(
    const u16* __restrict__ A, const u16* __restrict__ B,
    const float* __restrict__ bias,
    u16* __restrict__ oq, u16* __restrict__ ok, u16* __restrict__ ov,
    float* __restrict__ outf, int M, int N, int K)
{
    extern __shared__ char lds[];
    const int tid  = threadIdx.x;
    const int lane = tid & 63;
    const int wv   = tid >> 6;
    const int wm   = wv >> 2;          // 0..1 : 128-row half
    const int wn   = wv & 3;           // 0..3 : 64-col quarter
    const int bx = blockIdx.x, by = blockIdx.y;
    const int NT = K >> 6;

    const u16* Ab = A + (size_t)by * 256 * K;
    const u16* Bb = B + (size_t)bx * 256 * K;

    const int i  = lane & 15, g = lane >> 4;
    const int sw = (i & 3) ^ ((i >> 2) & 3);
    const int fo = ((g ^ sw) << 4);
    const int aoff = (wm * 128 + i) * 64 + fo;
    const int boff = (wn * 64 + i) * 64 + fo;

    f32x4 acc[8][4];
    #pragma unroll
    for (int m = 0; m < 8; ++m)
        #pragma unroll
        for (int n = 0; n < 4; ++n) {
            acc[m][n][0] = 0.f; acc[m][n][1] = 0.f;
            acc[m][n][2] = 0.f; acc[m][n][3] = 0.f;
        }

    // buffer layout: buf b at b*65536 ; slots A_k0 @0, B_k0 @16384, A_k1 @32768, B_k1 @49152
    // prologue: 6 half-tiles; after vmcnt(8) the steady-state queue is
    // [A_k1(0), B_k1(0), A_k0(1), B_k0(1)] (8 entries/thread).
    stage_half(Ab, K, 0,  lds + 0,             tid);
    stage_half(Bb, K, 0,  lds + 16384,         tid);
    stage_half(Ab, K, 32, lds + 32768,         tid);
    stage_half(Bb, K, 32, lds + 49152,         tid);
    stage_half(Ab, K, 64, lds + 65536 + 0,     tid);
    stage_half(Bb, K, 64, lds + 65536 + 16384, tid);
    VMCNT8();
    BARRIER();

    for (int t = 0; t < NT; ++t) {
        char* cb = lds + ((t & 1) << 16);
        char* nb = lds + (((t + 1) & 1) << 16);
        const int t1 = (t + 1 < NT) ? t + 1 : NT - 1;
        const int t2 = (t + 2 < NT) ? t + 2 : NT - 1;
        const int k1src = t1 * 64 + 32;
        const int k2src = t2 * 64;

        bf16x8 af0, af1, af2, af3, bf0, bf1, bf2, bf3;

        // ---- phase 1: k-half 0, rows m0..3 ----
        LOADA(cb, 0);
        LOADB(cb + 16384);
        stage_half(Ab, K, k1src, nb + 32768, tid);   // A_k1(t+1)
        BARRIER();
        LGKM0();
        __builtin_amdgcn_s_setprio(1);
        MFMA_BLOCK(0);
        __builtin_amdgcn_s_setprio(0);
        BARRIER();

        // ---- phase 2: k-half 0, rows m4..7 ----
        LOADA(cb, 4096);
        stage_half(Bb, K, k1src, nb + 49152, tid);   // B_k1(t+1)
        VMCNT8();                                    // drains A_k1(t), B_k1(t)
        BARRIER();
        LGKM0();
        __builtin_amdgcn_s_setprio(1);
        MFMA_BLOCK(4);
        __builtin_amdgcn_s_setprio(0);
        BARRIER();

        // ---- phase 3: k-half 1, rows m0..3 ----
        LOADA(cb + 32768, 0);
        LOADB(cb + 49152);
        stage_half(Ab, K, k2src, cb + 0, tid);       // A_k0(t+2) (slot consumed ph1/2)
        BARRIER();
        LGKM0();
        __builtin_amdgcn_s_setprio(1);
        MFMA_BLOCK(0);
        __builtin_amdgcn_s_setprio(0);
        BARRIER();

        // ---- phase 4: k-half 1, rows m4..7 ----
        LOADA(cb + 32768, 4096);
        stage_half(Bb, K, k2src, cb + 16384, tid);   // B_k0(t+2)
        VMCNT8();                                    // drains A_k0(t+1), B_k0(t+1)
        BARRIER();
        LGKM0();
        __builtin_amdgcn_s_setprio(1);
        MFMA_BLOCK(4);
        __builtin_amdgcn_s_setprio(0);
        BARRIER();
    }
    asm volatile("s_waitcnt vmcnt(0)" ::: "memory");  // drain tail stages before endpgm

    // epilogue: swapped-operand layout -> lane holds row (i) x 4 consecutive cols
    const int rowg0 = by * 256 + wm * 128;
    const int colg0 = bx * 256 + wn * 64;

    if (MODE == 1) {
        const int which = colg0 >> 10;               // uniform per wave
        u16* dst = (which == 0) ? oq : ((which == 1) ? ok : ov);
        const bool dophi = (which < 2);
        const int cbo = colg0 & 1023;
        #pragma unroll
        for (int n = 0; n < 4; ++n) {
            float4 bs = *(const float4*)(bias + colg0 + n * 16 + g * 4);
            #pragma unroll
            for (int m = 0; m < 8; ++m) {
                int row = rowg0 + m * 16 + i;
                float v0 = acc[m][n][0] + bs.x;
                float v1 = acc[m][n][1] + bs.y;
                float v2 = acc[m][n][2] + bs.z;
                float v3 = acc[m][n][3] + bs.w;
                if (dophi) {
                    v0 = (v0 > 0.f) ? (v0 + 1.f) : __expf(v0);
                    v1 = (v1 > 0.f) ? (v1 + 1.f) : __expf(v1);
                    v2 = (v2 > 0.f) ? (v2 + 1.f) : __expf(v2);
                    v3 = (v3 > 0.f) ? (v3 + 1.f) : __expf(v3);
                }
                ushort4 o;
                o.x = f2bf(v0); o.y = f2bf(v1); o.z = f2bf(v2); o.w = f2bf(v3);
                *(ushort4*)(dst + (size_t)row * 1024 + cbo + n * 16 + g * 4) = o;
            }
        }
    } else {
        #pragma unroll
        for (int n = 0; n < 4; ++n) {
            float4 bs = *(const float4*)(bias + colg0 + n * 16 + g * 4);
            #pragma unroll
            for (int m = 0; m < 8; ++m) {
                int row = rowg0 + m * 16 + i;
                float4 o;
                o.x = acc[m][n][0] + bs.x;
                o.y = acc[m][n][1] + bs.y;
                o.z = acc[m][n][2] + bs.z;
                o.w = acc[m][n][3] + bs.w;
                *(float4*)(outf + (size_t)row * N + colg0 + n * 16 + g * 4) = o;
            }
        }
    }
}

// ---------------- kv partial: kv[b,h,d,m] = sum_s k*v ; ksum[b,h,d] = sum_s k -----
__global__ __launch_bounds__(256) void kv_partial(
    const u16* __restrict__ kbf, const u16* __restrict__ vbf,
    const float* __restrict__ mask, float* __restrict__ kvp, float* __restrict__ ksp)
{
    const int bh = blockIdx.x, ch = blockIdx.y;
    const int b = bh >> 4, h = bh & 15;
    const int tid = threadIdx.x;
    __shared__ __align__(16) float ks[8][64];
    __shared__ __align__(16) float vs[8][64];
    const int dg = tid >> 4, mg = tid & 15;
    float acc[4][4] = {};
    float ksa[4] = {};
    const int s0 = ch * 256;
    const int jj = tid >> 6, e = tid & 63;
    for (int sb = 0; sb < 256; sb += 8) {
        #pragma unroll
        for (int r = jj; r < 8; r += 4) {
            size_t grow = (size_t)b * 4096 + (s0 + sb + r);
            float mm = mask[grow];
            size_t off = (grow << 10) + (h << 6) + e;
            ks[r][e] = bf2f(kbf[off]) * mm;
            vs[r][e] = bf2f(vbf[off]) * mm;
        }
        __syncthreads();
        #pragma unroll
        for (int ss = 0; ss < 8; ++ss) {
            float4 k4 = *(const float4*)&ks[ss][dg << 2];
            float4 v4 = *(const float4*)&vs[ss][mg << 2];
            float ka[4] = {k4.x, k4.y, k4.z, k4.w};
            float va[4] = {v4.x, v4.y, v4.z, v4.w};
            #pragma unroll
            for (int di = 0; di < 4; ++di) {
                ksa[di] += ka[di];
                #pragma unroll
                for (int mi = 0; mi < 4; ++mi) acc[di][mi] += ka[di] * va[mi];
            }
        }
        __syncthreads();
    }
    float* o = kvp + (((size_t)ch * 64 + bh) << 12);
    #pragma unroll
    for (int di = 0; di < 4; ++di)
        #pragma unroll
        for (int mi = 0; mi < 4; ++mi)
            o[(dg * 4 + di) * 64 + (mg * 4 + mi)] = acc[di][mi];
    if (mg == 0) {
        float* os = ksp + (((size_t)ch * 64 + bh) << 6);
        #pragma unroll
        for (int di = 0; di < 4; ++di) os[dg * 4 + di] = ksa[di];
    }
}

// ---------------- reduce 16 partials -> kv^T (bf16) + ksum (bf16) ----------------
__global__ __launch_bounds__(256) void kv_reduce(
    const float* __restrict__ kvp, const float* __restrict__ ksp,
    u16* __restrict__ kvTbf, u16* __restrict__ ksumbf)
{
    const int bh = blockIdx.x, tid = threadIdx.x;
    for (int idx = tid; idx < 4096; idx += 256) {
        float s = 0.f;
        #pragma unroll
        for (int c = 0; c < 16; ++c) s += kvp[(((size_t)c * 64 + bh) << 12) + idx];
        int d = idx >> 6, m = idx & 63;
        kvTbf[((size_t)bh << 12) + (m << 6) + d] = f2bf(s);   // transposed: [m][d]
    }
    if (tid < 64) {
        float s = 0.f;
        #pragma unroll
        for (int c = 0; c < 16; ++c) s += ksp[(((size_t)c * 64 + bh) << 6) + tid];
        ksumbf[(bh << 6) + tid] = f2bf(s);
    }
}

// ---------------- attn: out[s,m] = (sum_d q[s,d] kv[d,m]) / (q . ksum + eps) ------
__global__ __launch_bounds__(256) void attn_kernel(
    const u16* __restrict__ qbf, const u16* __restrict__ kvTbf,
    const u16* __restrict__ ksumbf, u16* __restrict__ attnbf)
{
    const int bh = blockIdx.x;
    const int b = bh >> 4, h = bh & 15;
    const int tid = threadIdx.x, lane = tid & 63, wv = tid >> 6;
    __shared__ __align__(16) u16 kvs[64 * 64];
    __shared__ __align__(16) u16 kss[64];

    {
        const uint4* src = (const uint4*)(kvTbf + ((size_t)bh << 12));
        for (int u = tid; u < 512; u += 256) {
            uint4 d4 = src[u];
            int m = u >> 3, slot = u & 7;
            *(uint4*)((char*)kvs + m * 128 + ((slot ^ (m & 7)) << 4)) = d4;
        }
        if (tid < 32)
            ((unsigned*)kss)[tid] = ((const unsigned*)(ksumbf + ((size_t)bh << 6)))[tid];
    }
    __syncthreads();

    bf16x8 bfr[2][4], bnf[2];
    #pragma unroll
    for (int kk = 0; kk < 2; ++kk) {
        int kslot = kk * 4 + (lane >> 4);
        #pragma unroll
        for (int n = 0; n < 4; ++n) {
            int m = n * 16 + (lane & 15);
            bfr[kk][n] = *(const bf16x8*)((const char*)kvs + m * 128 +
                                          ((kslot ^ (m & 7)) << 4));
        }
        #pragma unroll
        for (int i2 = 0; i2 < 8; ++i2) bnf[kk][i2] = (__bf16)0.0f;
        if ((lane & 15) == 0)
            bnf[kk] = *(const bf16x8*)((const char*)kss + (kslot << 4));
    }

    const int sbase = blockIdx.y * 256 + wv * 16;
    for (int it = 0; it < 4; ++it) {
        const int st = sbase + it * 64;
        f32x4 acc[4], nacc;
        #pragma unroll
        for (int n = 0; n < 4; ++n) {
            acc[n][0] = 0.f; acc[n][1] = 0.f; acc[n][2] = 0.f; acc[n][3] = 0.f;
        }
        nacc[0] = 0.f; nacc[1] = 0.f; nacc[2] = 0.f; nacc[3] = 0.f;
        #pragma unroll
        for (int kk = 0; kk < 2; ++kk) {
            size_t goff = (((size_t)(b * 4096 + st + (lane & 15))) << 10) +
                          (h << 6) + kk * 32 + ((lane >> 4) << 3);
            bf16x8 af = *(const bf16x8*)(qbf + goff);
            #pragma unroll
            for (int n = 0; n < 4; ++n)
                acc[n] = __builtin_amdgcn_mfma_f32_16x16x32_bf16(af, bfr[kk][n], acc[n], 0, 0, 0);
            nacc = __builtin_amdgcn_mfma_f32_16x16x32_bf16(af, bnf[kk], nacc, 0, 0, 0);
        }
        float inv[4];
        #pragma unroll
        for (int j = 0; j < 4; ++j) {
            float nj = __shfl(nacc[j], lane & 48);
            inv[j] = 1.0f / (nj + EPS_);
        }
        #pragma unroll
        for (int n = 0; n < 4; ++n)
            #pragma unroll
            for (int j = 0; j < 4; ++j) {
                int row = st + ((lane >> 4) << 2) + j;
                attnbf[(((size_t)(b * 4096 + row)) << 10) + (h << 6) + n * 16 + (lane & 15)]
                    = f2bf(acc[n][j] * inv[j]);
            }
    }
}

extern "C" void kernel_launch(void* const* d_in, const int* in_sizes, int n_in,
                              void* d_out, int out_size, void* d_ws, size_t ws_size,
                              hipStream_t stream) {
    const float* x    = (const float*)d_in[0];
    const float* mask = (const float*)d_in[1];
    const float* Wq   = (const float*)d_in[2];
    const float* bq   = (const float*)d_in[3];
    const float* Wk   = (const float*)d_in[4];
    const float* bk   = (const float*)d_in[5];
    const float* Wv   = (const float*)d_in[6];
    const float* bv   = (const float*)d_in[7];
    const float* Wo   = (const float*)d_in[8];
    const float* bo   = (const float*)d_in[9];
    float* out = (float*)d_out;

    if (ws_size < 142606336u) return;  // need 136 MiB

    char* ws = (char*)d_ws;
    // Phase A (projections): xbf [0,32MB) alive; weights/bias above it.
    u16*   xbf    = (u16*)ws;                     // 32 MB, dead after qkv gemm
    u16*   wqkvbf = (u16*)(ws + 33554432);        // 6 MB (Wq|Wk|Wv rows)
    float* bcat   = (float*)(ws + 39845888);      // 12 KB (bq|bk|bv)
    u16*   qbf    = (u16*)(ws + 41943040);        // 32 MB
    u16*   kbf    = qbf + 16777216;               // 32 MB
    u16*   vbf    = kbf + 16777216;               // 32 MB
    u16*   attnbf = kbf;                          // reuse (k dead after kv_partial)
    // Phase B (after qkv gemm, xbf dead): region [0,32MB) reused
    float* kvp    = (float*)ws;                   // 16 MB
    float* ksp    = (float*)(ws + 16777216);      // 256 KB
    u16*   kvTbf  = (u16*)(ws + 17039360);        // 512 KB
    u16*   ksumbf = (u16*)(ws + 17563648);        // 8 KB
    u16*   wobf   = (u16*)(ws + 20971520);        // 2 MB (converted after qkv gemm)

    // converts (x + fused qkv weights) and bias concat
    f32_to_bf16_kernel<<<16384, 256, 0, stream>>>(x,  xbf,  16777216 / 4);
    f32_to_bf16_kernel<<<1024,  256, 0, stream>>>(Wq, wqkvbf,           1048576 / 4);
    f32_to_bf16_kernel<<<1024,  256, 0, stream>>>(Wk, wqkvbf + 1048576, 1048576 / 4);
    f32_to_bf16_kernel<<<1024,  256, 0, stream>>>(Wv, wqkvbf + 2097152, 1048576 / 4);
    hipMemcpyAsync(bcat,        bq, 4096, hipMemcpyDeviceToDevice, stream);
    hipMemcpyAsync(bcat + 1024, bk, 4096, hipMemcpyDeviceToDevice, stream);
    hipMemcpyAsync(bcat + 2048, bv, 4096, hipMemcpyDeviceToDevice, stream);

    // fused QKV projection: [16384,1024] @ [3072,1024]^T, phi on q,k
    gemm8p<1><<<dim3(12, 64), 512, 131072, stream>>>(
        xbf, wqkvbf, bcat, qbf, kbf, vbf, nullptr, 16384, 3072, 1024);

    // Wo convert (xbf now dead; wobf lives in freed region)
    f32_to_bf16_kernel<<<1024, 256, 0, stream>>>(Wo, wobf, 1048576 / 4);

    // kv / ksum
    kv_partial<<<dim3(64, 16), 256, 0, stream>>>(kbf, vbf, mask, kvp, ksp);
    kv_reduce<<<64, 256, 0, stream>>>(kvp, ksp, kvTbf, ksumbf);

    // qkv + normalizer
    attn_kernel<<<dim3(64, 16), 256, 0, stream>>>(qbf, kvTbf, ksumbf, attnbf);

    // output projection -> fp32 d_out
    gemm8p<0><<<dim3(4, 64), 512, 131072, stream>>>(
        attnbf, wobf, bo, nullptr, nullptr, nullptr, out, 16384, 1024, 1024);
}

// Round 3
// 262.145 us; speedup vs baseline: 1.2359x; 1.0636x over previous
//
#include <hip/hip_runtime.h>

typedef unsigned short u16;
typedef float f32x4 __attribute__((ext_vector_type(4)));
typedef __bf16 bf16x8 __attribute__((ext_vector_type(8)));
typedef unsigned short us8 __attribute__((ext_vector_type(8)));

#define EPS_ 1e-6f

__device__ __forceinline__ u16 f2bf(float f) {
    unsigned u = __float_as_uint(f);
    u += 0x7FFFu + ((u >> 16) & 1u);   // round-to-nearest-even
    return (u16)(u >> 16);
}
__device__ __forceinline__ float bf2f(u16 h) {
    return __uint_as_float(((unsigned)h) << 16);
}
__device__ __forceinline__ void gload_lds16(const void* g, void* l) {
    __builtin_amdgcn_global_load_lds(
        (const __attribute__((address_space(1))) void*)g,
        (__attribute__((address_space(3))) void*)l, 16, 0, 0);
}

// ---------------- fp32 -> bf16 convert (vectorized) ----------------
__global__ __launch_bounds__(256) void f32_to_bf16_kernel(
    const float* __restrict__ src, u16* __restrict__ dst, int n4)
{
    int i = blockIdx.x * 256 + threadIdx.x;
    if (i >= n4) return;
    float4 f = ((const float4*)src)[i];
    ushort4 o;
    o.x = f2bf(f.x); o.y = f2bf(f.y); o.z = f2bf(f.z); o.w = f2bf(f.w);
    ((ushort4*)dst)[i] = o;
}

// =================================================================
// 256x256 8-phase GEMM, BK=64 split in two 32-k half-tiles (16KB each).
// LDS layout per half-tile (line-paired, bank-conflict rule: 8 consecutive
// lanes must hit 8 distinct 128B lines):
//   logical (row r in [0,256), k-chunk g in [0,4) of 8 bf16)
//   byte = (r&127)*128 + (r>>7)*64 + ((g ^ (r&3))<<4)
// Staging writes linearly (global_load_lds), source pre-permuted inversely.
// =================================================================

__device__ __forceinline__ void stage_half(
    const u16* __restrict__ src, int K, int kbase, char* slot, int tid)
{
    const int w = tid >> 6, l = tid & 63;
    #pragma unroll
    for (int j = 0; j < 2; ++j) {
        int c16 = j * 512 + w * 64 + l;       // 16B-chunk index 0..1023
        int L   = c16 >> 3;                   // 128B line
        int H   = (c16 >> 2) & 1;
        int c   = c16 & 3;
        int row = (H << 7) + L;               // logical row 0..255
        int ksrc = kbase + ((c ^ (row & 3)) << 3);
        gload_lds16(src + (size_t)row * K + ksrc, slot + j * 8192 + w * 1024);
    }
}

#define BARRIER()  asm volatile("s_barrier" ::: "memory")
#define VMCNT8()   asm volatile("s_waitcnt vmcnt(8)" ::: "memory")
#define LGKM0()    asm volatile("s_waitcnt lgkmcnt(0)" ::: "memory")

#define LOADA(base, MOFF) \
    af0 = *(const bf16x8*)((base) + aoff + (MOFF) + 0);    \
    af1 = *(const bf16x8*)((base) + aoff + (MOFF) + 2048); \
    af2 = *(const bf16x8*)((base) + aoff + (MOFF) + 4096); \
    af3 = *(const bf16x8*)((base) + aoff + (MOFF) + 6144);

#define LOADB(base) \
    bf0 = *(const bf16x8*)((base) + boff + 0);    \
    bf1 = *(const bf16x8*)((base) + boff + 2048); \
    bf2 = *(const bf16x8*)((base) + boff + 4096); \
    bf3 = *(const bf16x8*)((base) + boff + 6144);

#define MFMA1(M_, N_, AF_, BF_) \
    acc[M_][N_] = __builtin_amdgcn_mfma_f32_16x16x32_bf16(BF_, AF_, acc[M_][N_], 0, 0, 0)

#define MFMA_BLOCK(M0) do { \
    MFMA1(M0+0, 0, af0, bf0); MFMA1(M0+0, 1, af0, bf1); MFMA1(M0+0, 2, af0, bf2); MFMA1(M0+0, 3, af0, bf3); \
    MFMA1(M0+1, 0, af1, bf0); MFMA1(M0+1, 1, af1, bf1); MFMA1(M0+1, 2, af1, bf2); MFMA1(M0+1, 3, af1, bf3); \
    MFMA1(M0+2, 0, af2, bf0); MFMA1(M0+2, 1, af2, bf1); MFMA1(M0+2, 2, af2, bf2); MFMA1(M0+2, 3, af2, bf3); \
    MFMA1(M0+3, 0, af3, bf0); MFMA1(M0+3, 1, af3, bf1); MFMA1(M0+3, 2, af3, bf2); MFMA1(M0+3, 3, af3, bf3); \
} while (0)

template<int MODE>
__global__ __launch_bounds__(512, 2) void gemm8p(
    const u16* __restrict__ A, const u16* __restrict__ B,
    const float* __restrict__ bias,
    u16* __restrict__ oq, u16* __restrict__ ok, u16* __restrict__ ov,
    float* __restrict__ outf, int M, int N, int K)
{
    extern __shared__ char lds[];
    const int tid  = threadIdx.x;
    const int lane = tid & 63;
    const int wv   = tid >> 6;
    const int wm   = wv >> 2;          // 0..1 : 128-row half
    const int wn   = wv & 3;           // 0..3 : 64-col quarter
    const int NT = K >> 6;

    // bijective XCD chunk swizzle (nwg % 8 == 0 for both grids)
    int bx, by;
    {
        const int gx = gridDim.x;
        int wg  = blockIdx.y * gx + blockIdx.x;
        int cpx = (gx * gridDim.y) >> 3;
        int swz = (wg & 7) * cpx + (wg >> 3);
        bx = swz % gx; by = swz / gx;
    }

    const u16* Ab = A + (size_t)by * 256 * K;
    const u16* Bb = B + (size_t)bx * 256 * K;

    const int i  = lane & 15, g = lane >> 4;
    const int fo = ((g ^ (i & 3)) << 4);
    const int aoff = i * 128 + wm * 64 + fo;
    const int boff = ((wn & 1) * 64 + i) * 128 + (wn >> 1) * 64 + fo;

    f32x4 acc[8][4];
    #pragma unroll
    for (int m = 0; m < 8; ++m)
        #pragma unroll
        for (int n = 0; n < 4; ++n) {
            acc[m][n][0] = 0.f; acc[m][n][1] = 0.f;
            acc[m][n][2] = 0.f; acc[m][n][3] = 0.f;
        }

    // buffer b at b*65536: A_k0 @0, B_k0 @16384, A_k1 @32768, B_k1 @49152
    stage_half(Ab, K, 0,  lds + 0,             tid);
    stage_half(Bb, K, 0,  lds + 16384,         tid);
    stage_half(Ab, K, 32, lds + 32768,         tid);
    stage_half(Bb, K, 32, lds + 49152,         tid);
    stage_half(Ab, K, 64, lds + 65536 + 0,     tid);
    stage_half(Bb, K, 64, lds + 65536 + 16384, tid);
    VMCNT8();
    BARRIER();

    for (int t = 0; t < NT; ++t) {
        char* cb = lds + ((t & 1) << 16);
        char* nb = lds + (((t + 1) & 1) << 16);
        const int t1 = (t + 1 < NT) ? t + 1 : NT - 1;
        const int t2 = (t + 2 < NT) ? t + 2 : NT - 1;
        const int k1src = t1 * 64 + 32;
        const int k2src = t2 * 64;

        bf16x8 af0, af1, af2, af3, bf0, bf1, bf2, bf3;

        // ---- phase 1: k-half 0, rows m0..3 ----
        LOADA(cb, 0);
        LOADB(cb + 16384);
        stage_half(Ab, K, k1src, nb + 32768, tid);   // A_k1(t+1)
        BARRIER();
        LGKM0();
        __builtin_amdgcn_s_setprio(1);
        MFMA_BLOCK(0);
        __builtin_amdgcn_s_setprio(0);
        BARRIER();

        // ---- phase 2: k-half 0, rows m4..7 ----
        LOADA(cb, 8192);
        stage_half(Bb, K, k1src, nb + 49152, tid);   // B_k1(t+1)
        VMCNT8();                                    // k1(t) now landed
        BARRIER();
        LGKM0();
        __builtin_amdgcn_s_setprio(1);
        MFMA_BLOCK(4);
        __builtin_amdgcn_s_setprio(0);
        BARRIER();

        // ---- phase 3: k-half 1, rows m0..3 ----
        LOADA(cb + 32768, 0);
        LOADB(cb + 49152);
        stage_half(Ab, K, k2src, cb + 0, tid);       // A_k0(t+2)
        BARRIER();
        LGKM0();
        __builtin_amdgcn_s_setprio(1);
        MFMA_BLOCK(0);
        __builtin_amdgcn_s_setprio(0);
        BARRIER();

        // ---- phase 4: k-half 1, rows m4..7 ----
        LOADA(cb + 32768, 8192);
        stage_half(Bb, K, k2src, cb + 16384, tid);   // B_k0(t+2)
        VMCNT8();                                    // k0(t+1) now landed
        BARRIER();
        LGKM0();
        __builtin_amdgcn_s_setprio(1);
        MFMA_BLOCK(4);
        __builtin_amdgcn_s_setprio(0);
        BARRIER();
    }
    asm volatile("s_waitcnt vmcnt(0)" ::: "memory");

    // epilogue: lane holds row (i) x 4 consecutive cols (g*4..g*4+3)
    const int rowg0 = by * 256 + wm * 128;
    const int colg0 = bx * 256 + wn * 64;

    if (MODE == 1) {
        const int which = colg0 >> 10;               // uniform per wave
        u16* dst = (which == 0) ? oq : ((which == 1) ? ok : ov);
        const bool dophi = (which < 2);
        const int cbo = colg0 & 1023;
        float4 bs[4];
        #pragma unroll
        for (int n = 0; n < 4; ++n)
            bs[n] = *(const float4*)(bias + colg0 + n * 16 + g * 4);
        #pragma unroll
        for (int m = 0; m < 8; ++m) {
            int row = rowg0 + m * 16 + i;
            #pragma unroll
            for (int n = 0; n < 4; ++n) {
                float v0 = acc[m][n][0] + bs[n].x;
                float v1 = acc[m][n][1] + bs[n].y;
                float v2 = acc[m][n][2] + bs[n].z;
                float v3 = acc[m][n][3] + bs[n].w;
                if (dophi) {
                    v0 = (v0 > 0.f) ? (v0 + 1.f) : __expf(v0);
                    v1 = (v1 > 0.f) ? (v1 + 1.f) : __expf(v1);
                    v2 = (v2 > 0.f) ? (v2 + 1.f) : __expf(v2);
                    v3 = (v3 > 0.f) ? (v3 + 1.f) : __expf(v3);
                }
                ushort4 o;
                o.x = f2bf(v0); o.y = f2bf(v1); o.z = f2bf(v2); o.w = f2bf(v3);
                *(ushort4*)(dst + (size_t)row * 1024 + cbo + n * 16 + g * 4) = o;
            }
        }
    } else {
        float4 bs[4];
        #pragma unroll
        for (int n = 0; n < 4; ++n)
            bs[n] = *(const float4*)(bias + colg0 + n * 16 + g * 4);
        #pragma unroll
        for (int m = 0; m < 8; ++m) {
            int row = rowg0 + m * 16 + i;
            #pragma unroll
            for (int n = 0; n < 4; ++n) {
                float4 o;
                o.x = acc[m][n][0] + bs[n].x;
                o.y = acc[m][n][1] + bs[n].y;
                o.z = acc[m][n][2] + bs[n].z;
                o.w = acc[m][n][3] + bs[n].w;
                *(float4*)(outf + (size_t)row * N + colg0 + n * 16 + g * 4) = o;
            }
        }
    }
}

// ---------------- kv partial: kv[b,h,d,m] = sum_s k*v ; ksum[b,h,d] = sum_s k -----
// vectorized bf16x8 loads, 32-row LDS chunks
__global__ __launch_bounds__(256) void kv_partial(
    const u16* __restrict__ kbf, const u16* __restrict__ vbf,
    const float* __restrict__ mask, float* __restrict__ kvp, float* __restrict__ ksp)
{
    const int bh = blockIdx.x, ch = blockIdx.y;
    const int b = bh >> 4, h = bh & 15;
    const int tid = threadIdx.x;
    __shared__ __align__(16) float ks[32][64];
    __shared__ __align__(16) float vs[32][64];
    const int dg = tid >> 4, mg = tid & 15;
    float acc[4][4] = {};
    float ksa[4] = {};
    const int s0 = ch * 256;
    const int lr = tid >> 3, lc = (tid & 7) * 8;
    for (int sb = 0; sb < 256; sb += 32) {
        {
            size_t grow = (size_t)b * 4096 + (s0 + sb + lr);
            float mm = mask[grow];
            size_t off = (grow << 10) + (h << 6) + lc;
            us8 ku = __builtin_bit_cast(us8, *(const bf16x8*)(kbf + off));
            us8 vu = __builtin_bit_cast(us8, *(const bf16x8*)(vbf + off));
            #pragma unroll
            for (int j = 0; j < 8; ++j) {
                ks[lr][lc + j] = bf2f(ku[j]) * mm;
                vs[lr][lc + j] = bf2f(vu[j]) * mm;
            }
        }
        __syncthreads();
        #pragma unroll
        for (int ss = 0; ss < 32; ++ss) {
            float4 k4 = *(const float4*)&ks[ss][dg << 2];
            float4 v4 = *(const float4*)&vs[ss][mg << 2];
            float ka[4] = {k4.x, k4.y, k4.z, k4.w};
            float va[4] = {v4.x, v4.y, v4.z, v4.w};
            #pragma unroll
            for (int di = 0; di < 4; ++di) {
                ksa[di] += ka[di];
                #pragma unroll
                for (int mi = 0; mi < 4; ++mi) acc[di][mi] += ka[di] * va[mi];
            }
        }
        __syncthreads();
    }
    float* o = kvp + (((size_t)ch * 64 + bh) << 12);
    #pragma unroll
    for (int di = 0; di < 4; ++di)
        #pragma unroll
        for (int mi = 0; mi < 4; ++mi)
            o[(dg * 4 + di) * 64 + (mg * 4 + mi)] = acc[di][mi];
    if (mg == 0) {
        float* os = ksp + (((size_t)ch * 64 + bh) << 6);
        #pragma unroll
        for (int di = 0; di < 4; ++di) os[dg * 4 + di] = ksa[di];
    }
}

// ---------------- reduce 16 partials -> kv^T (bf16) + ksum (bf16) ----------------
__global__ __launch_bounds__(256) void kv_reduce(
    const float* __restrict__ kvp, const float* __restrict__ ksp,
    u16* __restrict__ kvTbf, u16* __restrict__ ksumbf)
{
    const int bh = blockIdx.x, tid = threadIdx.x;
    for (int idx = tid; idx < 4096; idx += 256) {
        float s = 0.f;
        #pragma unroll
        for (int c = 0; c < 16; ++c) s += kvp[(((size_t)c * 64 + bh) << 12) + idx];
        int d = idx >> 6, m = idx & 63;
        kvTbf[((size_t)bh << 12) + (m << 6) + d] = f2bf(s);   // transposed: [m][d]
    }
    if (tid < 64) {
        float s = 0.f;
        #pragma unroll
        for (int c = 0; c < 16; ++c) s += ksp[(((size_t)c * 64 + bh) << 6) + tid];
        ksumbf[(bh << 6) + tid] = f2bf(s);
    }
}

// ---------------- attn: out[s,m] = (sum_d q[s,d] kv[d,m]) / (q . ksum + eps) ------
__global__ __launch_bounds__(256) void attn_kernel(
    const u16* __restrict__ qbf, const u16* __restrict__ kvTbf,
    const u16* __restrict__ ksumbf, u16* __restrict__ attnbf)
{
    const int bh = blockIdx.x;
    const int b = bh >> 4, h = bh & 15;
    const int tid = threadIdx.x, lane = tid & 63, wv = tid >> 6;
    __shared__ __align__(16) u16 kvs[64 * 64];
    __shared__ __align__(16) u16 kss[64];

    {
        const uint4* src = (const uint4*)(kvTbf + ((size_t)bh << 12));
        for (int u = tid; u < 512; u += 256) {
            uint4 d4 = src[u];
            int m = u >> 3, slot = u & 7;
            *(uint4*)((char*)kvs + m * 128 + ((slot ^ (m & 7)) << 4)) = d4;
        }
        if (tid < 32)
            ((unsigned*)kss)[tid] = ((const unsigned*)(ksumbf + ((size_t)bh << 6)))[tid];
    }
    __syncthreads();

    bf16x8 bfr[2][4], bnf[2];
    #pragma unroll
    for (int kk = 0; kk < 2; ++kk) {
        int kslot = kk * 4 + (lane >> 4);
        #pragma unroll
        for (int n = 0; n < 4; ++n) {
            int m = n * 16 + (lane & 15);
            bfr[kk][n] = *(const bf16x8*)((const char*)kvs + m * 128 +
                                          ((kslot ^ (m & 7)) << 4));
        }
        #pragma unroll
        for (int i2 = 0; i2 < 8; ++i2) bnf[kk][i2] = (__bf16)0.0f;
        if ((lane & 15) == 0)
            bnf[kk] = *(const bf16x8*)((const char*)kss + (kslot << 4));
    }

    const int sbase = blockIdx.y * 256 + wv * 16;
    for (int it = 0; it < 4; ++it) {
        const int st = sbase + it * 64;
        f32x4 acc[4], nacc;
        #pragma unroll
        for (int n = 0; n < 4; ++n) {
            acc[n][0] = 0.f; acc[n][1] = 0.f; acc[n][2] = 0.f; acc[n][3] = 0.f;
        }
        nacc[0] = 0.f; nacc[1] = 0.f; nacc[2] = 0.f; nacc[3] = 0.f;
        #pragma unroll
        for (int kk = 0; kk < 2; ++kk) {
            size_t goff = (((size_t)(b * 4096 + st + (lane & 15))) << 10) +
                          (h << 6) + kk * 32 + ((lane >> 4) << 3);
            bf16x8 af = *(const bf16x8*)(qbf + goff);
            #pragma unroll
            for (int n = 0; n < 4; ++n)
                acc[n] = __builtin_amdgcn_mfma_f32_16x16x32_bf16(af, bfr[kk][n], acc[n], 0, 0, 0);
            nacc = __builtin_amdgcn_mfma_f32_16x16x32_bf16(af, bnf[kk], nacc, 0, 0, 0);
        }
        float inv[4];
        #pragma unroll
        for (int j = 0; j < 4; ++j) {
            float nj = __shfl(nacc[j], lane & 48);
            inv[j] = 1.0f / (nj + EPS_);
        }
        #pragma unroll
        for (int n = 0; n < 4; ++n)
            #pragma unroll
            for (int j = 0; j < 4; ++j) {
                int row = st + ((lane >> 4) << 2) + j;
                attnbf[(((size_t)(b * 4096 + row)) << 10) + (h << 6) + n * 16 + (lane & 15)]
                    = f2bf(acc[n][j] * inv[j]);
            }
    }
}

extern "C" void kernel_launch(void* const* d_in, const int* in_sizes, int n_in,
                              void* d_out, int out_size, void* d_ws, size_t ws_size,
                              hipStream_t stream) {
    const float* x    = (const float*)d_in[0];
    const float* mask = (const float*)d_in[1];
    const float* Wq   = (const float*)d_in[2];
    const float* bq   = (const float*)d_in[3];
    const float* Wk   = (const float*)d_in[4];
    const float* bk   = (const float*)d_in[5];
    const float* Wv   = (const float*)d_in[6];
    const float* bv   = (const float*)d_in[7];
    const float* Wo   = (const float*)d_in[8];
    const float* bo   = (const float*)d_in[9];
    float* out = (float*)d_out;

    if (ws_size < 142606336u) return;  // need 136 MiB

    char* ws = (char*)d_ws;
    u16*   xbf    = (u16*)ws;                     // 32 MB, dead after qkv gemm
    u16*   wqkvbf = (u16*)(ws + 33554432);        // 6 MB (Wq|Wk|Wv rows)
    float* bcat   = (float*)(ws + 39845888);      // 12 KB (bq|bk|bv)
    u16*   qbf    = (u16*)(ws + 41943040);        // 32 MB
    u16*   kbf    = qbf + 16777216;               // 32 MB
    u16*   vbf    = kbf + 16777216;               // 32 MB
    u16*   attnbf = kbf;                          // reuse (k dead after kv_partial)
    float* kvp    = (float*)ws;                   // 16 MB (after xbf dead)
    float* ksp    = (float*)(ws + 16777216);      // 256 KB
    u16*   kvTbf  = (u16*)(ws + 17039360);        // 512 KB
    u16*   ksumbf = (u16*)(ws + 17563648);        // 8 KB
    u16*   wobf   = (u16*)(ws + 20971520);        // 2 MB

    f32_to_bf16_kernel<<<16384, 256, 0, stream>>>(x,  xbf,  16777216 / 4);
    f32_to_bf16_kernel<<<1024,  256, 0, stream>>>(Wq, wqkvbf,           1048576 / 4);
    f32_to_bf16_kernel<<<1024,  256, 0, stream>>>(Wk, wqkvbf + 1048576, 1048576 / 4);
    f32_to_bf16_kernel<<<1024,  256, 0, stream>>>(Wv, wqkvbf + 2097152, 1048576 / 4);
    hipMemcpyAsync(bcat,        bq, 4096, hipMemcpyDeviceToDevice, stream);
    hipMemcpyAsync(bcat + 1024, bk, 4096, hipMemcpyDeviceToDevice, stream);
    hipMemcpyAsync(bcat + 2048, bv, 4096, hipMemcpyDeviceToDevice, stream);

    // fused QKV projection: [16384,1024] @ [3072,1024]^T, phi on q,k
    gemm8p<1><<<dim3(12, 64), 512, 131072, stream>>>(
        xbf, wqkvbf, bcat, qbf, kbf, vbf, nullptr, 16384, 3072, 1024);

    f32_to_bf16_kernel<<<1024, 256, 0, stream>>>(Wo, wobf, 1048576 / 4);

    kv_partial<<<dim3(64, 16), 256, 0, stream>>>(kbf, vbf, mask, kvp, ksp);
    kv_reduce<<<64, 256, 0, stream>>>(kvp, ksp, kvTbf, ksumbf);

    attn_kernel<<<dim3(64, 16), 256, 0, stream>>>(qbf, kvTbf, ksumbf, attnbf);

    gemm8p<0><<<dim3(4, 64), 512, 131072, stream>>>(
        attnbf, wobf, bo, nullptr, nullptr, nullptr, out, 16384, 1024, 1024);
}

// Round 4
// 242.316 us; speedup vs baseline: 1.3371x; 1.0818x over previous
//
#include <hip/hip_runtime.h>

typedef unsigned short u16;
typedef float f32x4 __attribute__((ext_vector_type(4)));
typedef __bf16 bf16x8 __attribute__((ext_vector_type(8)));
typedef unsigned short us8 __attribute__((ext_vector_type(8)));

#define EPS_ 1e-6f

__device__ __forceinline__ u16 f2bf(float f) {
    unsigned u = __float_as_uint(f);
    u += 0x7FFFu + ((u >> 16) & 1u);   // round-to-nearest-even
    return (u16)(u >> 16);
}
__device__ __forceinline__ float bf2f(u16 h) {
    return __uint_as_float(((unsigned)h) << 16);
}
__device__ __forceinline__ void gload_lds16(const void* g, void* l) {
    __builtin_amdgcn_global_load_lds(
        (const __attribute__((address_space(1))) void*)g,
        (__attribute__((address_space(3))) void*)l, 16, 0, 0);
}

// ---------------- fp32 -> bf16 convert (vectorized) ----------------
__global__ __launch_bounds__(256) void f32_to_bf16_kernel(
    const float* __restrict__ src, u16* __restrict__ dst, int n4)
{
    int i = blockIdx.x * 256 + threadIdx.x;
    if (i >= n4) return;
    float4 f = ((const float4*)src)[i];
    ushort4 o;
    o.x = f2bf(f.x); o.y = f2bf(f.y); o.z = f2bf(f.z); o.w = f2bf(f.w);
    ((ushort4*)dst)[i] = o;
}

// =================================================================
// 256x256 8-phase GEMM, BK=64 in two 32-k half-tile units (16KB each:
// 256 rows x 64B). LDS swizzle rule (HW, measured r1/r2/r3): within every
// 8-consecutive-lane group of a ds_read_b128, the 16B slot offsets mod 128B
// must be a full permutation of {0..7}.
//   byte(r,g) = r*64 + ((g ^ ((r>>1)&3)) << 4)
//   slot = ((r&1)<<2) | (g ^ ((r>>1)&3))  -> 8 distinct over 8 rows, g fixed.
// Staging writes linearly (global_load_lds); source pre-permuted with the
// same involution.
// =================================================================

__device__ __forceinline__ void stage_half(
    const u16* __restrict__ src, int K, int kbase, char* slot, int tid)
{
    const int w = tid >> 6, l = tid & 63;
    #pragma unroll
    for (int j = 0; j < 2; ++j) {
        int c16 = j * 512 + w * 64 + l;       // 16B-chunk index 0..1023
        int row = c16 >> 2;                   // logical row 0..255
        int sl  = c16 & 3;
        int ksrc = kbase + ((sl ^ ((row >> 1) & 3)) << 3);
        gload_lds16(src + (size_t)row * K + ksrc, slot + j * 8192 + w * 1024);
    }
}

#define BARRIER()  asm volatile("s_barrier" ::: "memory")
#define VMCNT8()   asm volatile("s_waitcnt vmcnt(8)" ::: "memory")
#define LGKM0()    asm volatile("s_waitcnt lgkmcnt(0)" ::: "memory")

#define LOADA(base, MOFF) \
    af0 = *(const bf16x8*)((base) + aoff + (MOFF) + 0);    \
    af1 = *(const bf16x8*)((base) + aoff + (MOFF) + 1024); \
    af2 = *(const bf16x8*)((base) + aoff + (MOFF) + 2048); \
    af3 = *(const bf16x8*)((base) + aoff + (MOFF) + 3072);

#define LOADB(base) \
    bf0 = *(const bf16x8*)((base) + boff + 0);    \
    bf1 = *(const bf16x8*)((base) + boff + 1024); \
    bf2 = *(const bf16x8*)((base) + boff + 2048); \
    bf3 = *(const bf16x8*)((base) + boff + 3072);

#define MFMA1(M_, N_, AF_, BF_) \
    acc[M_][N_] = __builtin_amdgcn_mfma_f32_16x16x32_bf16(BF_, AF_, acc[M_][N_], 0, 0, 0)

#define MFMA_BLOCK(M0) do { \
    MFMA1(M0+0, 0, af0, bf0); MFMA1(M0+0, 1, af0, bf1); MFMA1(M0+0, 2, af0, bf2); MFMA1(M0+0, 3, af0, bf3); \
    MFMA1(M0+1, 0, af1, bf0); MFMA1(M0+1, 1, af1, bf1); MFMA1(M0+1, 2, af1, bf2); MFMA1(M0+1, 3, af1, bf3); \
    MFMA1(M0+2, 0, af2, bf0); MFMA1(M0+2, 1, af2, bf1); MFMA1(M0+2, 2, af2, bf2); MFMA1(M0+2, 3, af2, bf3); \
    MFMA1(M0+3, 0, af3, bf0); MFMA1(M0+3, 1, af3, bf1); MFMA1(M0+3, 2, af3, bf2); MFMA1(M0+3, 3, af3, bf3); \
} while (0)

template<int MODE>
__global__ __launch_bounds__(512, 2) void gemm8p(
    const u16* __restrict__ A, const u16* __restrict__ B,
    const float* __restrict__ bias,
    u16* __restrict__ oq, u16* __restrict__ ok, u16* __restrict__ ov,
    float* __restrict__ outf, int M, int N, int K)
{
    extern __shared__ char lds[];
    const int tid  = threadIdx.x;
    const int lane = tid & 63;
    const int wv   = tid >> 6;
    const int wm   = wv >> 2;          // 0..1 : 128-row half
    const int wn   = wv & 3;           // 0..3 : 64-col quarter
    const int NT = K >> 6;

    // bijective XCD chunk swizzle (nwg % 8 == 0 for both grids)
    int bx, by;
    {
        const int gx = gridDim.x;
        int wg  = blockIdx.y * gx + blockIdx.x;
        int cpx = (gx * gridDim.y) >> 3;
        int swz = (wg & 7) * cpx + (wg >> 3);
        bx = swz % gx; by = swz / gx;
    }

    const u16* Ab = A + (size_t)by * 256 * K;
    const u16* Bb = B + (size_t)bx * 256 * K;

    const int i  = lane & 15, g = lane >> 4;
    const int fo = ((g ^ ((i >> 1) & 3)) << 4);
    const int aoff = (wm * 128 + i) * 64 + fo;
    const int boff = (wn * 64 + i) * 64 + fo;

    f32x4 acc[8][4];
    #pragma unroll
    for (int m = 0; m < 8; ++m)
        #pragma unroll
        for (int n = 0; n < 4; ++n) {
            acc[m][n][0] = 0.f; acc[m][n][1] = 0.f;
            acc[m][n][2] = 0.f; acc[m][n][3] = 0.f;
        }

    // buffer b at b*65536: A_k0 @0, B_k0 @16384, A_k1 @32768, B_k1 @49152
    stage_half(Ab, K, 0,  lds + 0,             tid);
    stage_half(Bb, K, 0,  lds + 16384,         tid);
    stage_half(Ab, K, 32, lds + 32768,         tid);
    stage_half(Bb, K, 32, lds + 49152,         tid);
    stage_half(Ab, K, 64, lds + 65536 + 0,     tid);
    stage_half(Bb, K, 64, lds + 65536 + 16384, tid);
    VMCNT8();
    BARRIER();

    for (int t = 0; t < NT; ++t) {
        char* cb = lds + ((t & 1) << 16);
        char* nb = lds + (((t + 1) & 1) << 16);
        const int t1 = (t + 1 < NT) ? t + 1 : NT - 1;
        const int t2 = (t + 2 < NT) ? t + 2 : NT - 1;
        const int k1src = t1 * 64 + 32;
        const int k2src = t2 * 64;

        bf16x8 af0, af1, af2, af3, bf0, bf1, bf2, bf3;

        // ---- phase 1: k-half 0, rows m0..3 ----
        LOADA(cb, 0);
        LOADB(cb + 16384);
        stage_half(Ab, K, k1src, nb + 32768, tid);   // A_k1(t+1)
        BARRIER();
        LGKM0();
        __builtin_amdgcn_s_setprio(1);
        MFMA_BLOCK(0);
        __builtin_amdgcn_s_setprio(0);
        BARRIER();

        // ---- phase 2: k-half 0, rows m4..7 ----
        LOADA(cb, 4096);
        stage_half(Bb, K, k1src, nb + 49152, tid);   // B_k1(t+1)
        VMCNT8();                                    // k1(t) now landed
        BARRIER();
        LGKM0();
        __builtin_amdgcn_s_setprio(1);
        MFMA_BLOCK(4);
        __builtin_amdgcn_s_setprio(0);
        BARRIER();

        // ---- phase 3: k-half 1, rows m0..3 ----
        LOADA(cb + 32768, 0);
        LOADB(cb + 49152);
        stage_half(Ab, K, k2src, cb + 0, tid);       // A_k0(t+2)
        BARRIER();
        LGKM0();
        __builtin_amdgcn_s_setprio(1);
        MFMA_BLOCK(0);
        __builtin_amdgcn_s_setprio(0);
        BARRIER();

        // ---- phase 4: k-half 1, rows m4..7 ----
        LOADA(cb + 32768, 4096);
        stage_half(Bb, K, k2src, cb + 16384, tid);   // B_k0(t+2)
        VMCNT8();                                    // k0(t+1) now landed
        BARRIER();
        LGKM0();
        __builtin_amdgcn_s_setprio(1);
        MFMA_BLOCK(4);
        __builtin_amdgcn_s_setprio(0);
        BARRIER();
    }
    asm volatile("s_waitcnt vmcnt(0)" ::: "memory");

    // epilogue: lane holds row (i) x 4 consecutive cols (g*4..g*4+3)
    const int rowg0 = by * 256 + wm * 128;
    const int colg0 = bx * 256 + wn * 64;

    if (MODE == 1) {
        const int which = colg0 >> 10;               // uniform per wave
        u16* dst = (which == 0) ? oq : ((which == 1) ? ok : ov);
        const bool dophi = (which < 2);
        const int cbo = colg0 & 1023;
        float4 bs[4];
        #pragma unroll
        for (int n = 0; n < 4; ++n)
            bs[n] = *(const float4*)(bias + colg0 + n * 16 + g * 4);
        #pragma unroll
        for (int m = 0; m < 8; ++m) {
            int row = rowg0 + m * 16 + i;
            #pragma unroll
            for (int n = 0; n < 4; ++n) {
                float v0 = acc[m][n][0] + bs[n].x;
                float v1 = acc[m][n][1] + bs[n].y;
                float v2 = acc[m][n][2] + bs[n].z;
                float v3 = acc[m][n][3] + bs[n].w;
                if (dophi) {
                    v0 = (v0 > 0.f) ? (v0 + 1.f) : __expf(v0);
                    v1 = (v1 > 0.f) ? (v1 + 1.f) : __expf(v1);
                    v2 = (v2 > 0.f) ? (v2 + 1.f) : __expf(v2);
                    v3 = (v3 > 0.f) ? (v3 + 1.f) : __expf(v3);
                }
                ushort4 o;
                o.x = f2bf(v0); o.y = f2bf(v1); o.z = f2bf(v2); o.w = f2bf(v3);
                *(ushort4*)(dst + (size_t)row * 1024 + cbo + n * 16 + g * 4) = o;
            }
        }
    } else {
        float4 bs[4];
        #pragma unroll
        for (int n = 0; n < 4; ++n)
            bs[n] = *(const float4*)(bias + colg0 + n * 16 + g * 4);
        #pragma unroll
        for (int m = 0; m < 8; ++m) {
            int row = rowg0 + m * 16 + i;
            #pragma unroll
            for (int n = 0; n < 4; ++n) {
                float4 o;
                o.x = acc[m][n][0] + bs[n].x;
                o.y = acc[m][n][1] + bs[n].y;
                o.z = acc[m][n][2] + bs[n].z;
                o.w = acc[m][n][3] + bs[n].w;
                *(float4*)(outf + (size_t)row * N + colg0 + n * 16 + g * 4) = o;
            }
        }
    }
}

// ---------------- kv partial: kv[b,h,d,m] = sum_s k*v ; ksum[b,h,d] = sum_s k -----
__global__ __launch_bounds__(256) void kv_partial(
    const u16* __restrict__ kbf, const u16* __restrict__ vbf,
    const float* __restrict__ mask, float* __restrict__ kvp, float* __restrict__ ksp)
{
    const int bh = blockIdx.x, ch = blockIdx.y;
    const int b = bh >> 4, h = bh & 15;
    const int tid = threadIdx.x;
    __shared__ __align__(16) float ks[32][64];
    __shared__ __align__(16) float vs[32][64];
    const int dg = tid >> 4, mg = tid & 15;
    float acc[4][4] = {};
    float ksa[4] = {};
    const int s0 = ch * 256;
    const int lr = tid >> 3, lc = (tid & 7) * 8;
    for (int sb = 0; sb < 256; sb += 32) {
        {
            size_t grow = (size_t)b * 4096 + (s0 + sb + lr);
            float mm = mask[grow];
            size_t off = (grow << 10) + (h << 6) + lc;
            us8 ku = __builtin_bit_cast(us8, *(const bf16x8*)(kbf + off));
            us8 vu = __builtin_bit_cast(us8, *(const bf16x8*)(vbf + off));
            #pragma unroll
            for (int j = 0; j < 8; ++j) {
                ks[lr][lc + j] = bf2f(ku[j]) * mm;
                vs[lr][lc + j] = bf2f(vu[j]) * mm;
            }
        }
        __syncthreads();
        #pragma unroll
        for (int ss = 0; ss < 32; ++ss) {
            float4 k4 = *(const float4*)&ks[ss][dg << 2];
            float4 v4 = *(const float4*)&vs[ss][mg << 2];
            float ka[4] = {k4.x, k4.y, k4.z, k4.w};
            float va[4] = {v4.x, v4.y, v4.z, v4.w};
            #pragma unroll
            for (int di = 0; di < 4; ++di) {
                ksa[di] += ka[di];
                #pragma unroll
                for (int mi = 0; mi < 4; ++mi) acc[di][mi] += ka[di] * va[mi];
            }
        }
        __syncthreads();
    }
    float* o = kvp + (((size_t)ch * 64 + bh) << 12);
    #pragma unroll
    for (int di = 0; di < 4; ++di)
        #pragma unroll
        for (int mi = 0; mi < 4; ++mi)
            o[(dg * 4 + di) * 64 + (mg * 4 + mi)] = acc[di][mi];
    if (mg == 0) {
        float* os = ksp + (((size_t)ch * 64 + bh) << 6);
        #pragma unroll
        for (int di = 0; di < 4; ++di) os[dg * 4 + di] = ksa[di];
    }
}

// ---------------- reduce 16 partials -> kv^T (bf16) + ksum (bf16) ----------------
__global__ __launch_bounds__(256) void kv_reduce(
    const float* __restrict__ kvp, const float* __restrict__ ksp,
    u16* __restrict__ kvTbf, u16* __restrict__ ksumbf)
{
    const int bh = blockIdx.x, tid = threadIdx.x;
    for (int idx = tid; idx < 4096; idx += 256) {
        float s = 0.f;
        #pragma unroll
        for (int c = 0; c < 16; ++c) s += kvp[(((size_t)c * 64 + bh) << 12) + idx];
        int d = idx >> 6, m = idx & 63;
        kvTbf[((size_t)bh << 12) + (m << 6) + d] = f2bf(s);   // transposed: [m][d]
    }
    if (tid < 64) {
        float s = 0.f;
        #pragma unroll
        for (int c = 0; c < 16; ++c) s += ksp[(((size_t)c * 64 + bh) << 6) + tid];
        ksumbf[(bh << 6) + tid] = f2bf(s);
    }
}

// ---------------- attn: out[s,m] = (sum_d q[s,d] kv[d,m]) / (q . ksum + eps) ------
__global__ __launch_bounds__(256) void attn_kernel(
    const u16* __restrict__ qbf, const u16* __restrict__ kvTbf,
    const u16* __restrict__ ksumbf, u16* __restrict__ attnbf)
{
    const int bh = blockIdx.x;
    const int b = bh >> 4, h = bh & 15;
    const int tid = threadIdx.x, lane = tid & 63, wv = tid >> 6;
    __shared__ __align__(16) u16 kvs[64 * 64];
    __shared__ __align__(16) u16 kss[64];

    {
        const uint4* src = (const uint4*)(kvTbf + ((size_t)bh << 12));
        for (int u = tid; u < 512; u += 256) {
            uint4 d4 = src[u];
            int m = u >> 3, slot = u & 7;
            *(uint4*)((char*)kvs + m * 128 + ((slot ^ (m & 7)) << 4)) = d4;
        }
        if (tid < 32)
            ((unsigned*)kss)[tid] = ((const unsigned*)(ksumbf + ((size_t)bh << 6)))[tid];
    }
    __syncthreads();

    bf16x8 bfr[2][4], bnf[2];
    #pragma unroll
    for (int kk = 0; kk < 2; ++kk) {
        int kslot = kk * 4 + (lane >> 4);
        #pragma unroll
        for (int n = 0; n < 4; ++n) {
            int m = n * 16 + (lane & 15);
            bfr[kk][n] = *(const bf16x8*)((const char*)kvs + m * 128 +
                                          ((kslot ^ (m & 7)) << 4));
        }
        #pragma unroll
        for (int i2 = 0; i2 < 8; ++i2) bnf[kk][i2] = (__bf16)0.0f;
        if ((lane & 15) == 0)
            bnf[kk] = *(const bf16x8*)((const char*)kss + (kslot << 4));
    }

    const int sbase = blockIdx.y * 256 + wv * 16;
    for (int it = 0; it < 4; ++it) {
        const int st = sbase + it * 64;
        f32x4 acc[4], nacc;
        #pragma unroll
        for (int n = 0; n < 4; ++n) {
            acc[n][0] = 0.f; acc[n][1] = 0.f; acc[n][2] = 0.f; acc[n][3] = 0.f;
        }
        nacc[0] = 0.f; nacc[1] = 0.f; nacc[2] = 0.f; nacc[3] = 0.f;
        #pragma unroll
        for (int kk = 0; kk < 2; ++kk) {
            size_t goff = (((size_t)(b * 4096 + st + (lane & 15))) << 10) +
                          (h << 6) + kk * 32 + ((lane >> 4) << 3);
            bf16x8 af = *(const bf16x8*)(qbf + goff);
            #pragma unroll
            for (int n = 0; n < 4; ++n)
                acc[n] = __builtin_amdgcn_mfma_f32_16x16x32_bf16(af, bfr[kk][n], acc[n], 0, 0, 0);
            nacc = __builtin_amdgcn_mfma_f32_16x16x32_bf16(af, bnf[kk], nacc, 0, 0, 0);
        }
        float inv[4];
        #pragma unroll
        for (int j = 0; j < 4; ++j) {
            float nj = __shfl(nacc[j], lane & 48);
            inv[j] = 1.0f / (nj + EPS_);
        }
        #pragma unroll
        for (int n = 0; n < 4; ++n)
            #pragma unroll
            for (int j = 0; j < 4; ++j) {
                int row = st + ((lane >> 4) << 2) + j;
                attnbf[(((size_t)(b * 4096 + row)) << 10) + (h << 6) + n * 16 + (lane & 15)]
                    = f2bf(acc[n][j] * inv[j]);
            }
    }
}

extern "C" void kernel_launch(void* const* d_in, const int* in_sizes, int n_in,
                              void* d_out, int out_size, void* d_ws, size_t ws_size,
                              hipStream_t stream) {
    const float* x    = (const float*)d_in[0];
    const float* mask = (const float*)d_in[1];
    const float* Wq   = (const float*)d_in[2];
    const float* bq   = (const float*)d_in[3];
    const float* Wk   = (const float*)d_in[4];
    const float* bk   = (const float*)d_in[5];
    const float* Wv   = (const float*)d_in[6];
    const float* bv   = (const float*)d_in[7];
    const float* Wo   = (const float*)d_in[8];
    const float* bo   = (const float*)d_in[9];
    float* out = (float*)d_out;

    if (ws_size < 142606336u) return;  // need 136 MiB

    char* ws = (char*)d_ws;
    u16*   xbf    = (u16*)ws;                     // 32 MB, dead after qkv gemm
    u16*   wqkvbf = (u16*)(ws + 33554432);        // 6 MB (Wq|Wk|Wv rows)
    float* bcat   = (float*)(ws + 39845888);      // 12 KB (bq|bk|bv)
    u16*   qbf    = (u16*)(ws + 41943040);        // 32 MB
    u16*   kbf    = qbf + 16777216;               // 32 MB
    u16*   vbf    = kbf + 16777216;               // 32 MB
    u16*   attnbf = kbf;                          // reuse (k dead after kv_partial)
    float* kvp    = (float*)ws;                   // 16 MB (after xbf dead)
    float* ksp    = (float*)(ws + 16777216);      // 256 KB
    u16*   kvTbf  = (u16*)(ws + 17039360);        // 512 KB
    u16*   ksumbf = (u16*)(ws + 17563648);        // 8 KB
    u16*   wobf   = (u16*)(ws + 20971520);        // 2 MB

    f32_to_bf16_kernel<<<16384, 256, 0, stream>>>(x,  xbf,  16777216 / 4);
    f32_to_bf16_kernel<<<1024,  256, 0, stream>>>(Wq, wqkvbf,           1048576 / 4);
    f32_to_bf16_kernel<<<1024,  256, 0, stream>>>(Wk, wqkvbf + 1048576, 1048576 / 4);
    f32_to_bf16_kernel<<<1024,  256, 0, stream>>>(Wv, wqkvbf + 2097152, 1048576 / 4);
    hipMemcpyAsync(bcat,        bq, 4096, hipMemcpyDeviceToDevice, stream);
    hipMemcpyAsync(bcat + 1024, bk, 4096, hipMemcpyDeviceToDevice, stream);
    hipMemcpyAsync(bcat + 2048, bv, 4096, hipMemcpyDeviceToDevice, stream);

    // fused QKV projection: [16384,1024] @ [3072,1024]^T, phi on q,k
    gemm8p<1><<<dim3(12, 64), 512, 131072, stream>>>(
        xbf, wqkvbf, bcat, qbf, kbf, vbf, nullptr, 16384, 3072, 1024);

    f32_to_bf16_kernel<<<1024, 256, 0, stream>>>(Wo, wobf, 1048576 / 4);

    kv_partial<<<dim3(64, 16), 256, 0, stream>>>(kbf, vbf, mask, kvp, ksp);
    kv_reduce<<<64, 256, 0, stream>>>(kvp, ksp, kvTbf, ksumbf);

    attn_kernel<<<dim3(64, 16), 256, 0, stream>>>(qbf, kvTbf, ksumbf, attnbf);

    gemm8p<0><<<dim3(4, 64), 512, 131072, stream>>>(
        attnbf, wobf, bo, nullptr, nullptr, nullptr, out, 16384, 1024, 1024);
}